// Round 1
// baseline (419.125 us; speedup 1.0000x reference)
//
#include <hip/hip_runtime.h>

#define CAP 128

typedef __attribute__((ext_vector_type(8))) short bf16x8;
typedef __attribute__((ext_vector_type(4))) float f32x4;

__device__ __forceinline__ unsigned short f2bf(float f) {
    unsigned u = __float_as_uint(f);
    u += 0x7FFFu + ((u >> 16) & 1u);
    return (unsigned short)(u >> 16);
}
__device__ __forceinline__ float bf2f(unsigned short h) {
    return __uint_as_float(((unsigned)h) << 16);
}

// ---------------- fp32 -> bf16 conversion (hp, hq, 12 weights) ----------------
struct CvtSeg { const float* s; unsigned short* d; int n4; };
struct CvtArgs { CvtSeg seg[14]; };

__global__ __launch_bounds__(256) void cvt_kernel(CvtArgs c) {
    int gid = blockIdx.x * 256 + threadIdx.x;
    int stride = gridDim.x * 256;
    #pragma unroll
    for (int si = 0; si < 14; ++si) {
        CvtSeg sg = c.seg[si];
        for (int i = gid; i < sg.n4; i += stride) {
            float4 v = ((const float4*)sg.s)[i];
            ushort4 o;
            o.x = f2bf(v.x); o.y = f2bf(v.y); o.z = f2bf(v.z); o.w = f2bf(v.w);
            ((ushort4*)sg.d)[i] = o;
        }
    }
}

// ---------------- dense 0/1 adjacency -> per-row index lists ----------------
struct ExtArgs { const float* a0; const float* a1; const float* a2; const float* a3; int* idx; int* cnt; };

__global__ __launch_bounds__(256) void extract_kernel(ExtArgs e) {
    int row = blockIdx.x, m = blockIdx.y, t = threadIdx.x;
    const float* A = (m == 0) ? e.a0 : (m == 1) ? e.a1 : (m == 2) ? e.a2 : e.a3;
    const float4* rp = (const float4*)(A + (size_t)row * 8192);
    float4 vals[8];
    int cnt = 0;
    #pragma unroll
    for (int it = 0; it < 8; ++it) {
        float4 v = rp[it * 256 + t];   // 4 KB coalesced per iteration
        vals[it] = v;
        cnt += (v.x != 0.f) + (v.y != 0.f) + (v.z != 0.f) + (v.w != 0.f);
    }
    __shared__ int ssc[256];
    ssc[t] = cnt;
    __syncthreads();
    #pragma unroll
    for (int off = 1; off < 256; off <<= 1) {
        int v = (t >= off) ? ssc[t - off] : 0;
        __syncthreads();
        ssc[t] += v;
        __syncthreads();
    }
    int o = ssc[t] - cnt;            // exclusive prefix
    int* op = e.idx + ((size_t)m * 8192 + row) * CAP;
    #pragma unroll
    for (int it = 0; it < 8; ++it) {
        float4 v = vals[it];
        int j = it * 1024 + t * 4;
        if (v.x != 0.f) { if (o < CAP) op[o] = j;     o++; }
        if (v.y != 0.f) { if (o < CAP) op[o] = j + 1; o++; }
        if (v.z != 0.f) { if (o < CAP) op[o] = j + 2; o++; }
        if (v.w != 0.f) { if (o < CAP) op[o] = j + 3; o++; }
    }
    if (t == 255) {
        int total = ssc[255];
        e.cnt[m * 8192 + row] = total < CAP ? total : CAP;
    }
}

// ---------------- 6 linears in one launch: Z = bf16(X @ W^T + b) ----------------
struct GemmDesc { const unsigned short* X; const unsigned short* W; const float* bias; unsigned short* Z; };
struct GemmArgs { GemmDesc d[6]; };

template<int K>
__global__ __launch_bounds__(256) void gemm6_kernel(GemmArgs ga) {
    GemmDesc g = ga.d[blockIdx.z];
    int wave = threadIdx.x >> 6;
    int lane = threadIdx.x & 63;
    int r = lane & 15, q = lane >> 4;
    int rowbase = blockIdx.x * 128 + wave * 32;   // 64 blocks * 128 rows = 8192
    int colbase = blockIdx.y * 64;                // 4 blocks * 64 cols = 256
    f32x4 acc[2][4] = {};
    const unsigned short* xp0 = g.X + (size_t)(rowbase + r) * K + q * 8;
    const unsigned short* xp1 = xp0 + (size_t)16 * K;
    const unsigned short* wbase = g.W + (size_t)(colbase + r) * K + q * 8;
    #pragma unroll
    for (int k0 = 0; k0 < K; k0 += 32) {
        bf16x8 a0 = *(const bf16x8*)(xp0 + k0);
        bf16x8 a1 = *(const bf16x8*)(xp1 + k0);
        #pragma unroll
        for (int nt = 0; nt < 4; ++nt) {
            bf16x8 b = *(const bf16x8*)(wbase + (size_t)nt * 16 * K + k0);
            acc[0][nt] = __builtin_amdgcn_mfma_f32_16x16x32_bf16(a0, b, acc[0][nt], 0, 0, 0);
            acc[1][nt] = __builtin_amdgcn_mfma_f32_16x16x32_bf16(a1, b, acc[1][nt], 0, 0, 0);
        }
    }
    // C/D layout: col = lane&15, row = (lane>>4)*4 + reg   [guide §3, m89-verified]
    #pragma unroll
    for (int mt = 0; mt < 2; ++mt) {
        #pragma unroll
        for (int nt = 0; nt < 4; ++nt) {
            int col = colbase + nt * 16 + r;
            float bv = g.bias[col];
            #pragma unroll
            for (int j = 0; j < 4; ++j) {
                int row = rowbase + mt * 16 + q * 4 + j;
                g.Z[(size_t)row * 256 + col] = f2bf(acc[mt][nt][j] + bv);
            }
        }
    }
}

// ---------------- fused self + 2 SpMM gathers + leaky_relu (+ optional L2-norm) ----------------
struct AggSide {
    const unsigned short* zself;
    const unsigned short* za;
    const unsigned short* zb;
    const int* idxa; const int* cnta;
    const int* idxb; const int* cntb;
    unsigned short* out_bf;
    float* out_f;
};

template<int FINAL>
__global__ __launch_bounds__(256) void agg_kernel(AggSide s0, AggSide s1) {
    AggSide s = blockIdx.y ? s1 : s0;
    int wave = threadIdx.x >> 6, lane = threadIdx.x & 63;
    int row = blockIdx.x * 4 + wave;              // one wave per output row
    int c4 = lane * 4;
    ushort4 v = *(const ushort4*)(s.zself + (size_t)row * 256 + c4);
    float a0 = bf2f(v.x), a1 = bf2f(v.y), a2 = bf2f(v.z), a3 = bf2f(v.w);
    int ca = s.cnta[row], cb = s.cntb[row];
    const int* ia = s.idxa + (size_t)row * CAP;
    const int* ib = s.idxb + (size_t)row * CAP;
    #pragma unroll 4
    for (int k = 0; k < ca; ++k) {
        ushort4 w = *(const ushort4*)(s.za + (size_t)ia[k] * 256 + c4);
        a0 += bf2f(w.x); a1 += bf2f(w.y); a2 += bf2f(w.z); a3 += bf2f(w.w);
    }
    #pragma unroll 4
    for (int k = 0; k < cb; ++k) {
        ushort4 w = *(const ushort4*)(s.zb + (size_t)ib[k] * 256 + c4);
        a0 += bf2f(w.x); a1 += bf2f(w.y); a2 += bf2f(w.z); a3 += bf2f(w.w);
    }
    a0 = a0 > 0.f ? a0 : 0.1f * a0;
    a1 = a1 > 0.f ? a1 : 0.1f * a1;
    a2 = a2 > 0.f ? a2 : 0.1f * a2;
    a3 = a3 > 0.f ? a3 : 0.1f * a3;
    if (FINAL) {
        float ss = a0 * a0 + a1 * a1 + a2 * a2 + a3 * a3;
        #pragma unroll
        for (int off = 32; off > 0; off >>= 1) ss += __shfl_xor(ss, off);
        float sc = 1.0f / (sqrtf(ss) + 1e-9f);
        float4 o; o.x = a0 * sc; o.y = a1 * sc; o.z = a2 * sc; o.w = a3 * sc;
        *(float4*)(s.out_f + (size_t)row * 256 + c4) = o;
    } else {
        ushort4 o; o.x = f2bf(a0); o.y = f2bf(a1); o.z = f2bf(a2); o.w = f2bf(a3);
        *(ushort4*)(s.out_bf + (size_t)row * 256 + c4) = o;
    }
}

extern "C" void kernel_launch(void* const* d_in, const int* in_sizes, int n_in,
                              void* d_out, int out_size, void* d_ws, size_t ws_size,
                              hipStream_t stream) {
    const float* hp         = (const float*)d_in[0];
    const float* hq         = (const float*)d_in[1];
    const float* a_cons     = (const float*)d_in[2];
    const float* a_prod     = (const float*)d_in[3];
    const float* a_rev_cons = (const float*)d_in[4];
    const float* a_rev_prod = (const float*)d_in[5];

    char* ws = (char*)d_ws;
    constexpr size_t SZ_H   = (size_t)8192 * 512 * 2;   // bf16 hp/hq
    constexpr size_t SZ_W1  = (size_t)256 * 512 * 2;
    constexpr size_t SZ_W2  = (size_t)256 * 256 * 2;
    constexpr size_t SZ_Z   = (size_t)8192 * 256 * 2;   // bf16 z / h1
    constexpr size_t OFF_HP  = 0;
    constexpr size_t OFF_HQ  = OFF_HP + SZ_H;
    constexpr size_t OFF_WBF = OFF_HQ + SZ_H;
    constexpr size_t OFF_IDX = OFF_WBF + 6 * SZ_W1 + 6 * SZ_W2;
    constexpr size_t OFF_CNT = OFF_IDX + (size_t)4 * 8192 * CAP * 4;
    constexpr size_t OFF_Z   = OFF_CNT + (size_t)4 * 8192 * 4;
    constexpr size_t OFF_H1P = OFF_Z + 6 * SZ_Z;
    constexpr size_t OFF_H1Q = OFF_H1P + SZ_Z;

    unsigned short* hp_bf = (unsigned short*)(ws + OFF_HP);
    unsigned short* hq_bf = (unsigned short*)(ws + OFF_HQ);
    int* idx = (int*)(ws + OFF_IDX);
    int* cnt = (int*)(ws + OFF_CNT);
    unsigned short* z[6];
    for (int i = 0; i < 6; ++i) z[i] = (unsigned short*)(ws + OFF_Z + i * SZ_Z);
    unsigned short* h1p = (unsigned short*)(ws + OFF_H1P);
    unsigned short* h1q = (unsigned short*)(ws + OFF_H1Q);

    // bf16 weight slots: l1: 0 wp1, 1 wcons1, 2 wrprod1, 3 wq1, 4 wprod1, 5 wrcons1
    //                    l2: 6 wp2, 7 wcons2, 8 wrprod2, 9 wq2, 10 wprod2, 11 wrcons2
    unsigned short* wbf[12];
    for (int i = 0; i < 6; ++i) wbf[i]     = (unsigned short*)(ws + OFF_WBF + i * SZ_W1);
    for (int i = 0; i < 6; ++i) wbf[6 + i] = (unsigned short*)(ws + OFF_WBF + 6 * SZ_W1 + i * SZ_W2);

    CvtArgs ca;
    ca.seg[0] = { hp, hp_bf, 8192 * 512 / 4 };
    ca.seg[1] = { hq, hq_bf, 8192 * 512 / 4 };
    const int wIdxL1[6] = { 6, 10, 12, 8, 14, 16 };   // wp1, wcons1, wrprod1, wq1, wprod1, wrcons1
    const int wIdxL2[6] = { 18, 22, 24, 20, 26, 28 }; // wp2, wcons2, wrprod2, wq2, wprod2, wrcons2
    for (int i = 0; i < 6; ++i) ca.seg[2 + i] = { (const float*)d_in[wIdxL1[i]], wbf[i],     256 * 512 / 4 };
    for (int i = 0; i < 6; ++i) ca.seg[8 + i] = { (const float*)d_in[wIdxL2[i]], wbf[6 + i], 256 * 256 / 4 };
    cvt_kernel<<<dim3(1024), dim3(256), 0, stream>>>(ca);

    ExtArgs ea = { a_cons, a_prod, a_rev_cons, a_rev_prod, idx, cnt };
    extract_kernel<<<dim3(8192, 4), dim3(256), 0, stream>>>(ea);

    // layer 1 linears (K=512)
    GemmArgs g1;
    g1.d[0] = { hp_bf, wbf[0], (const float*)d_in[7],  z[0] };
    g1.d[1] = { hq_bf, wbf[1], (const float*)d_in[11], z[1] };
    g1.d[2] = { hq_bf, wbf[2], (const float*)d_in[13], z[2] };
    g1.d[3] = { hq_bf, wbf[3], (const float*)d_in[9],  z[3] };
    g1.d[4] = { hp_bf, wbf[4], (const float*)d_in[15], z[4] };
    g1.d[5] = { hp_bf, wbf[5], (const float*)d_in[17], z[5] };
    gemm6_kernel<512><<<dim3(64, 4, 6), dim3(256), 0, stream>>>(g1);

    int* idx0 = idx + (size_t)0 * 8192 * CAP;  // a_cons      (P rows over Q)
    int* idx1 = idx + (size_t)1 * 8192 * CAP;  // a_prod      (Q rows over P)
    int* idx2 = idx + (size_t)2 * 8192 * CAP;  // a_rev_cons  (Q rows over P)
    int* idx3 = idx + (size_t)3 * 8192 * CAP;  // a_rev_prod  (P rows over Q)
    int* cnt0 = cnt, *cnt1 = cnt + 8192, *cnt2 = cnt + 16384, *cnt3 = cnt + 24576;

    AggSide p1 = { z[0], z[1], z[2], idx0, cnt0, idx3, cnt3, h1p, nullptr };
    AggSide q1 = { z[3], z[4], z[5], idx1, cnt1, idx2, cnt2, h1q, nullptr };
    agg_kernel<0><<<dim3(2048, 2), dim3(256), 0, stream>>>(p1, q1);

    // layer 2 linears (K=256)
    GemmArgs g2;
    g2.d[0] = { h1p, wbf[6],  (const float*)d_in[19], z[0] };
    g2.d[1] = { h1q, wbf[7],  (const float*)d_in[23], z[1] };
    g2.d[2] = { h1q, wbf[8],  (const float*)d_in[25], z[2] };
    g2.d[3] = { h1q, wbf[9],  (const float*)d_in[21], z[3] };
    g2.d[4] = { h1p, wbf[10], (const float*)d_in[27], z[4] };
    g2.d[5] = { h1p, wbf[11], (const float*)d_in[29], z[5] };
    gemm6_kernel<256><<<dim3(64, 4, 6), dim3(256), 0, stream>>>(g2);

    float* outp = (float*)d_out;
    AggSide p2 = { z[0], z[1], z[2], idx0, cnt0, idx3, cnt3, nullptr, outp };
    AggSide q2 = { z[3], z[4], z[5], idx1, cnt1, idx2, cnt2, nullptr, outp + (size_t)8192 * 256 };
    agg_kernel<1><<<dim3(2048, 2), dim3(256), 0, stream>>>(p2, q2);
}